// Round 11
// baseline (1122.844 us; speedup 1.0000x reference)
//
#include <hip/hip_runtime.h>
#include <cmath>

// RecurrentGCN: GATv2Conv -> GConvGRU(1 step, H0=0) -> per-node MLP.
// Algebraic simplifications (verified against reference):
//  * H0=0  => cheb(H,...)=bias only; R unused (R*H=0); H_new=(1-Z)*Ht
//  * Z = sigmoid(cheb(h,W[0],b[0]) + b[1]);  Ht = tanh(cheb(h,W[4],b[4]) + b[5])
//  * both chebs share Tx0..Tx3 (3 sparse matvecs total)
//  * MLPAggregation: out[k>0] = relu(H[k-1]@W1[:16]+b1)@W2+b2 ; out[0] from H=0
// R6 lesson: scattered float atomics = 6x regression (899MB RMW traffic).
// R8 (this structure) = 794us total; k_gat 166us @ VGPR=220, Occ=10.7% ->
// latency-bound gathers. R9 changes: (1) k_gat occupancy: launch_bounds(256,3),
// xr row in LDS, branchless online-softmax; (2) k_gat emits compact coalesced
// ssrc[] so the 3 Cheb SpMV passes stream 4B/lane instead of 8B-strided int2;
// (3) hist fused into node-transform kernel (one less launch).

constexpr int N = 50000;
constexpr int E = 1600000;
constexpr int NT_BLOCKS = N / 16;            // 3125

// ---- fused: blocks [0,NT_BLOCKS) do xl/xr transform; rest do degree hist ----
__global__ __launch_bounds__(256)
void k_pre(const float* __restrict__ x,
           const float* __restrict__ Wl, const float* __restrict__ bl,
           const float* __restrict__ Wr, const float* __restrict__ br,
           float* __restrict__ xl, float* __restrict__ xr,
           const int* __restrict__ ei, int* __restrict__ cnt_in,
           int* __restrict__ deg_out) {
    if ((int)blockIdx.x >= NT_BLOCKS) {      // histogram part (6250 blocks)
        int e = ((int)blockIdx.x - NT_BLOCKS) * 256 + threadIdx.x;
        int s = ei[e], d = ei[E + e];
        atomicAdd(&cnt_in[d], 1);
        if (s != d) atomicAdd(&deg_out[s], 1);
        return;
    }
    __shared__ float sWl[128 * 16];
    __shared__ float sWr[128 * 16];
    int t = threadIdx.x;
    for (int i = t; i < 2048; i += 256) { sWl[i] = Wl[i]; sWr[i] = Wr[i]; }
    __syncthreads();
    int f = t & 15, nl = t >> 4;
    int n = blockIdx.x * 16 + nl;
    const float4* xv = reinterpret_cast<const float4*>(x + (size_t)n * 128);
    float aL = bl[f], aR = br[f];
#pragma unroll 8
    for (int k4 = 0; k4 < 32; ++k4) {
        float4 v = xv[k4];
        int k = k4 * 4;
        aL += v.x * sWl[(k + 0) * 16 + f]; aR += v.x * sWr[(k + 0) * 16 + f];
        aL += v.y * sWl[(k + 1) * 16 + f]; aR += v.y * sWr[(k + 1) * 16 + f];
        aL += v.z * sWl[(k + 2) * 16 + f]; aR += v.z * sWr[(k + 2) * 16 + f];
        aL += v.w * sWl[(k + 3) * 16 + f]; aR += v.w * sWr[(k + 3) * 16 + f];
    }
    xl[n * 16 + f] = aL;
    xr[n * 16 + f] = aR;
}

// ---------------- exclusive scan of cnt_in -> rowptr (single block) ----------------
__global__ __launch_bounds__(1024)
void k_scan(const int* __restrict__ cnt, int* __restrict__ rowptr, int n) {
    __shared__ int ssum[1024];
    int t = threadIdx.x;
    const int chunk = 52;
    int lo = t * chunk;
    int hi = lo + chunk; if (hi > n) hi = n; if (lo > n) lo = n;
    int s = 0;
    for (int i = lo; i + 3 < hi; i += 4) {
        int4 v = *reinterpret_cast<const int4*>(cnt + i);
        s += v.x + v.y + v.z + v.w;
    }
    ssum[t] = s;
    __syncthreads();
    for (int off = 1; off < 1024; off <<= 1) {
        int v = (t >= off) ? ssum[t - off] : 0;
        __syncthreads();
        ssum[t] += v;
        __syncthreads();
    }
    int prefix = (t == 0) ? 0 : ssum[t - 1];
    for (int i = lo; i < hi; ++i) { rowptr[i] = prefix; prefix += cnt[i]; }
    if (t == 0) rowptr[n] = ssum[1023];
}

// ---------------- CSR placement ONLY: one packed 8B scatter per edge ----------
__global__ __launch_bounds__(256)
void k_edge_place(const int* __restrict__ ei, const int* __restrict__ rowptr,
                  int* __restrict__ ctr, int2* __restrict__ sedge) {
    int e = blockIdx.x * 256 + threadIdx.x;  // grid = E/256 exact
    int s = ei[e], d = ei[E + e];
    int p = rowptr[d] + atomicAdd(&ctr[d], 1);
    sedge[p] = make_int2(s, e);              // {src, eid}
}

// ---- fused per-node GAT, single pass, edge-parallel lanes, BRANCHLESS online
//      softmax; xr row broadcast from LDS; emits compact ssrc[] stream. ----
__global__ __launch_bounds__(256, 3)
void k_gat(const int* __restrict__ rowptr, const int2* __restrict__ sedge,
           const float* __restrict__ ea, const float* __restrict__ xl,
           const float* __restrict__ xr, const int* __restrict__ deg_out,
           const float* __restrict__ We, const float* __restrict__ att,
           const float* __restrict__ gat_bias,
           const float* __restrict__ Wz0, const float* __restrict__ Wh0,
           int* __restrict__ ssrc,
           float* __restrict__ h, float* __restrict__ hs,
           float* __restrict__ accz, float* __restrict__ acch,
           float* __restrict__ dinv) {
    __shared__ float sWe[256], sWz[256], sWh[256];
    __shared__ float satt[16];
    __shared__ float sxr[16][17];            // per-node xr row (broadcast reads)
    __shared__ float strans[16][16][17];     // [node][lane][feat(+pad)]
    __shared__ float sbuf[16][17];
    int t = threadIdx.x;
    sWe[t] = We[t]; sWz[t] = Wz0[t]; sWh[t] = Wh0[t];
    if (t < 16) satt[t] = att[t];
    int f = t & 15, nl = t >> 4;
    int n = blockIdx.x * 16 + nl;            // grid = N/16 exact
    sxr[nl][f] = xr[n * 16 + f];
    __syncthreads();
    int lo = rowptr[n], hi = rowptr[n + 1];
    float m_l = -3.0e38f, den_l = 0.f;
    float num_l[16], emacc[16];
#pragma unroll
    for (int j = 0; j < 16; ++j) { num_l[j] = 0.f; emacc[j] = 0.f; }
    for (int i = lo + f; i < hi; i += 16) {
        int2 se = sedge[i];                  // coalesced within group
        ssrc[i] = se.x;                      // compact stream for SpMV passes
        const float4* ea4 = reinterpret_cast<const float4*>(ea + (size_t)se.y * 16);
        const float4* xl4 = reinterpret_cast<const float4*>(xl + (size_t)se.x * 16);
        float a[16], xs[16];
#pragma unroll
        for (int j = 0; j < 4; ++j) {
            float4 v = ea4[j]; a[4*j] = v.x; a[4*j+1] = v.y; a[4*j+2] = v.z; a[4*j+3] = v.w;
            float4 u = xl4[j]; xs[4*j] = u.x; xs[4*j+1] = u.y; xs[4*j+2] = u.z; xs[4*j+3] = u.w;
        }
        float alpha = 0.f;
#pragma unroll
        for (int f2 = 0; f2 < 16; ++f2) {
            float e2 = 0.f;
#pragma unroll
            for (int j = 0; j < 16; ++j) e2 += a[j] * sWe[j * 16 + f2];
            emacc[f2] += e2;
            float m = xs[f2] + sxr[nl][f2] + e2;
            m = m > 0.f ? m : 0.2f * m;      // leaky_relu 0.2
            alpha += m * satt[f2];
        }
        // branchless online-softmax update (first edge: corr=exp(-inf)=0)
        float mnew = fmaxf(m_l, alpha);
        float corr = expf(m_l - mnew);
        float ex   = expf(alpha - mnew);
        den_l = den_l * corr + ex;
#pragma unroll
        for (int j = 0; j < 16; ++j) num_l[j] = num_l[j] * corr + ex * xs[j];
        m_l = mnew;
    }
    // combine 16 lanes: global max, rescale, reduce
    float M = m_l;
#pragma unroll
    for (int off = 1; off < 16; off <<= 1) M = fmaxf(M, __shfl_xor(M, off, 64));
    float s_l = expf(m_l - M);               // empty lane: 0 (or 1*den0=0)
    float den = den_l * s_l;
#pragma unroll
    for (int off = 1; off < 16; off <<= 1) den += __shfl_xor(den, off, 64);
    // transpose-reduce num (lane-major -> feature-major)
#pragma unroll
    for (int j = 0; j < 16; ++j) strans[nl][f][j] = num_l[j] * s_l;
    __syncthreads();
    float num_f = 0.f;
#pragma unroll
    for (int j = 0; j < 16; ++j) num_f += strans[nl][j][f];
    __syncthreads();
#pragma unroll
    for (int j = 0; j < 16; ++j) strans[nl][f][j] = emacc[j];
    __syncthreads();
    float emsum_f = 0.f;
#pragma unroll
    for (int j = 0; j < 16; ++j) emsum_f += strans[nl][j][f];
    // self-loop alpha via linearity: ea_mean@We = emsum/cnt
    float cntf = (float)(hi - lo);
    float xlf = xl[n * 16 + f];
    float xrf = sxr[nl][f];
    float m0 = xlf + xrf + emsum_f / fmaxf(cntf, 1.f);
    m0 = m0 > 0.f ? m0 : 0.2f * m0;
    float c = m0 * satt[f];
#pragma unroll
    for (int off = 1; off < 16; off <<= 1) c += __shfl_xor(c, off, 64);
    float aloop = c;
    float Mf = fmaxf(M, aloop);
    float sc2 = expf(M - Mf);                // no-edge node: 0
    float exl = expf(aloop - Mf);
    num_f = num_f * sc2 + exl * xlf;
    float dent = den * sc2 + exl;
    float hv = num_f / (dent + 1e-16f) + gat_bias[f];
    float dg = (float)deg_out[n];
    float di = dg > 0.f ? rsqrtf(dg) : 0.f;
    h[n * 16 + f] = hv;
    hs[n * 16 + f] = di * hv;                // pre-scaled for cheb matvec
    if (f == 0) dinv[n] = di;
    // acc init = h @ W[.][0]
    sbuf[nl][f] = hv;
    __syncthreads();
    float az = 0.f, ah = 0.f;
#pragma unroll
    for (int j = 0; j < 16; ++j) {
        float v = sbuf[nl][j];
        az += v * sWz[j * 16 + f];
        ah += v * sWh[j * 16 + f];
    }
    accz[n * 16 + f] = az;
    acch[n * 16 + f] = ah;
}

// ---- fused Cheb step: mv[n] = -dinv[n]*sum_{s!=n} Tins[s];
//      tv = mode ? 2*mv - Tprev : mv; optional stores; acc += tv@W[k] ----
__global__ __launch_bounds__(256)
void k_mvcomb(const int* __restrict__ rowptr, const int* __restrict__ ssrc,
              const float* __restrict__ dinv, const float* __restrict__ Tins,
              const float* __restrict__ Tprev, float* __restrict__ Tstore,
              float* __restrict__ Tscale_store,
              const float* __restrict__ Wzk, const float* __restrict__ Whk,
              float* __restrict__ accz, float* __restrict__ acch, int mode) {
    __shared__ float sWz[256], sWh[256];
    __shared__ float st[16][17];
    int t = threadIdx.x;
    sWz[t] = Wzk[t]; sWh[t] = Whk[t];
    int f = t & 15, nl = t >> 4;
    int n = blockIdx.x * 16 + nl;            // grid = N/16 exact
    int lo = rowptr[n], hi = rowptr[n + 1];
    float acc = 0.f;
    for (int i = lo; i < hi; ++i) {
        int s = ssrc[i];                     // 4B coalesced-ish broadcast
        if (s != n) acc += Tins[s * 16 + f]; // Tins already dinv-scaled
    }
    float di = dinv[n];
    float tv = -di * acc;
    if (mode) tv = 2.f * tv - Tprev[n * 16 + f];
    if (Tstore)       Tstore[n * 16 + f] = tv;
    if (Tscale_store) Tscale_store[n * 16 + f] = di * tv;
    st[nl][f] = tv;
    __syncthreads();
    float az = accz[n * 16 + f], ah = acch[n * 16 + f];
#pragma unroll
    for (int j = 0; j < 16; ++j) {
        float v = st[nl][j];
        az += v * sWz[j * 16 + f];
        ah += v * sWh[j * 16 + f];
    }
    accz[n * 16 + f] = az;
    acch[n * 16 + f] = ah;
}

// ---- last Cheb step fused with GRU combine + per-node MLP + out row 0 ----
__global__ __launch_bounds__(256)
void k_mvfinal(const int* __restrict__ rowptr, const int* __restrict__ ssrc,
               const float* __restrict__ dinv, const float* __restrict__ Tins,
               const float* __restrict__ Tprev,
               const float* __restrict__ Wzk, const float* __restrict__ Whk,
               const float* __restrict__ accz, const float* __restrict__ acch,
               const float* __restrict__ cheb_b,
               const float* __restrict__ W1, const float* __restrict__ b1,
               const float* __restrict__ W2, const float* __restrict__ b2,
               float* __restrict__ out) {
    __shared__ float sWz[256], sWh[256];
    __shared__ float st[16][17];
    int t = threadIdx.x;
    sWz[t] = Wzk[t]; sWh[t] = Whk[t];
    int f = t & 15, nl = t >> 4;
    int n = blockIdx.x * 16 + nl;            // grid = N/16 exact
    int lo = rowptr[n], hi = rowptr[n + 1];
    float acc = 0.f;
    for (int i = lo; i < hi; ++i) {
        int s = ssrc[i];
        if (s != n) acc += Tins[s * 16 + f];
    }
    float tv = -dinv[n] * acc;
    tv = 2.f * tv - Tprev[n * 16 + f];        // T3 = 2 L T2 - T1
    st[nl][f] = tv;
    __syncthreads();
    float az = accz[n * 16 + f], ah = acch[n * 16 + f];
#pragma unroll
    for (int j = 0; j < 16; ++j) {
        float v = st[nl][j];
        az += v * sWz[j * 16 + f];
        ah += v * sWh[j * 16 + f];
    }
    // GRU (H0=0): Z = sigmoid(az + b[0] + b[1]); Ht = tanh(ah + b[4] + b[5])
    float z  = 1.f / (1.f + expf(-(az + cheb_b[f] + cheb_b[16 + f])));
    float ht = tanhf(ah + cheb_b[64 + f] + cheb_b[80 + f]);
    float H = (1.f - z) * ht;
    __syncthreads();                          // reuse st
    st[nl][f] = H;
    __syncthreads();
    float hid[4];
#pragma unroll
    for (int cc = 0; cc < 4; ++cc) {
        float v = b1[cc];
#pragma unroll
        for (int j = 0; j < 16; ++j) v += st[nl][j] * W1[j * 4 + cc];
        hid[cc] = fmaxf(v, 0.f);
    }
    if (f < 8) {
        float v = b2[f];
#pragma unroll
        for (int cc = 0; cc < 4; ++cc) v += hid[cc] * W2[cc * 8 + f];
        out[(size_t)(n + 1) * 8 + f] = v;
    }
    if (blockIdx.x == 0 && t == 0) {          // segment 0 is empty -> H = 0
        float h0[4];
#pragma unroll
        for (int cc = 0; cc < 4; ++cc) h0[cc] = fmaxf(b1[cc], 0.f);
#pragma unroll
        for (int o = 0; o < 8; ++o) {
            float v = b2[o];
#pragma unroll
            for (int cc = 0; cc < 4; ++cc) v += h0[cc] * W2[cc * 8 + o];
            out[o] = v;
        }
    }
}

extern "C" void kernel_launch(void* const* d_in, const int* in_sizes, int n_in,
                              void* d_out, int out_size, void* d_ws, size_t ws_size,
                              hipStream_t stream) {
    const float* x    = (const float*)d_in[0];
    const int*   ei   = (const int*)d_in[1];
    const float* ea   = (const float*)d_in[2];
    const float* Wl   = (const float*)d_in[3];
    const float* bl   = (const float*)d_in[4];
    const float* Wr   = (const float*)d_in[5];
    const float* br   = (const float*)d_in[6];
    const float* We   = (const float*)d_in[7];
    const float* att  = (const float*)d_in[8];
    const float* gatb = (const float*)d_in[9];
    const float* chW  = (const float*)d_in[10];  // [6][4][16][16]
    const float* chb  = (const float*)d_in[11];  // [6][16]
    const float* W1   = (const float*)d_in[12];
    const float* b1   = (const float*)d_in[13];
    const float* W2   = (const float*)d_in[14];
    const float* b2   = (const float*)d_in[15];
    float* out = (float*)d_out;

    char* w = (char*)d_ws;
    size_t off = 0;
    auto alloc = [&](size_t elems) {
        off = (off + 15) & ~(size_t)15;       // keep float4/int2 alignment
        void* p = w + off;
        off += elems * 4;
        return p;
    };
    // zeroed region: cnt_in / deg_out / ctr contiguous (3N ints)
    int*   cnt_in  = (int*)alloc(N);
    int*   deg_out = (int*)alloc(N);
    int*   ctr     = (int*)alloc(N);
    int*   rowptr  = (int*)alloc(N + 2);
    float* xl      = (float*)alloc(16 * N);
    float* xr      = (float*)alloc(16 * N);
    int2*  sedge   = (int2*)alloc(2 * (size_t)E);  // {src, eid} packed
    int*   ssrc    = (int*)alloc(E);          // compact src stream (CSR order)
    float* dinv    = (float*)alloc(N);
    float* h       = (float*)alloc(16 * N);
    float* hs      = (float*)alloc(16 * N);   // dinv-scaled h
    float* accz    = (float*)alloc(16 * N);
    float* acch    = (float*)alloc(16 * N);
    float* T1      = (float*)alloc(16 * N);   // unscaled T1 (Tprev for step 3)
    float* Tsa     = (float*)alloc(16 * N);   // scaled current
    float* Tsb     = (float*)alloc(16 * N);
    (void)ws_size; (void)in_sizes; (void)n_in; (void)out_size;

    hipMemsetAsync(cnt_in, 0, (size_t)3 * N * sizeof(int), stream);

    k_pre<<<NT_BLOCKS + E / 256, 256, 0, stream>>>(x, Wl, bl, Wr, br, xl, xr,
                                                   ei, cnt_in, deg_out);
    k_scan<<<1, 1024, 0, stream>>>(cnt_in, rowptr, N);
    k_edge_place<<<E / 256, 256, 0, stream>>>(ei, rowptr, ctr, sedge);
    // cheb_W block k of cheb index i is at (i*4+k)*256 ; i=0 -> z path, i=4 -> h path
    k_gat<<<N / 16, 256, 0, stream>>>(rowptr, sedge, ea, xl, xr, deg_out, We, att,
                                      gatb, chW + 0 * 256, chW + 16 * 256,
                                      ssrc, h, hs, accz, acch, dinv);
    // T1 = L h            ; acc += T1@W[1]   (store T1 unscaled + scaled)
    k_mvcomb<<<N / 16, 256, 0, stream>>>(rowptr, ssrc, dinv, hs, (const float*)nullptr,
                                         T1, Tsa, chW + 1 * 256, chW + 17 * 256,
                                         accz, acch, 0);
    // T2 = 2 L T1 - h     ; acc += T2@W[2]   (store scaled only)
    k_mvcomb<<<N / 16, 256, 0, stream>>>(rowptr, ssrc, dinv, Tsa, h,
                                         (float*)nullptr, Tsb, chW + 2 * 256, chW + 18 * 256,
                                         accz, acch, 1);
    // T3 = 2 L T2 - T1 fused with GRU + MLP + out
    k_mvfinal<<<N / 16, 256, 0, stream>>>(rowptr, ssrc, dinv, Tsb, T1,
                                          chW + 3 * 256, chW + 19 * 256,
                                          accz, acch, chb, W1, b1, W2, b2, out);
}

// Round 16
// 791.747 us; speedup vs baseline: 1.4182x; 1.4182x over previous
//
#include <hip/hip_runtime.h>
#include <cmath>

// RecurrentGCN: GATv2Conv -> GConvGRU(1 step, H0=0) -> per-node MLP.
// Algebraic simplifications (verified against reference):
//  * H0=0  => cheb(H,...)=bias only; R unused (R*H=0); H_new=(1-Z)*Ht
//  * Z = sigmoid(cheb(h,W[0],b[0]) + b[1]);  Ht = tanh(cheb(h,W[4],b[4]) + b[5])
//  * both chebs share Tx0..Tx3 (3 sparse matvecs total)
//  * MLPAggregation: out[k>0] = relu(H[k-1]@W1[:16]+b1)@W2+b2 ; out[0] from H=0
// Ledger: R6 scattered float atomics = 6x regression (899MB RMW).
//         R8 edge-parallel-lane k_gat = 166us @ VGPR220 (latency-bound).
//         R11 forced launch_bounds(256,3) = spill catastrophe (FETCH 1.3GB,
//             WRITE 842MB, 535us) -- the 64-float/lane accumulator state is
//             the root cause, not the bound.
// R12: k_gat switched to FEATURE-parallel lanes: per-edge loads are broadcast
// (sedge) or coalesced 64B rows (ea, xl); em via 16 shfl-broadcasts; alpha via
// 4-shfl reduce (wave-uniform) -> online-softmax state is 4 scalars/lane.
// No strans transpose buffer; ssrc dropped (SpMV reads sedge.x, L3-resident).

constexpr int N = 50000;
constexpr int E = 1600000;
constexpr int NT_BLOCKS = N / 16;            // 3125

// ---- fused: blocks [0,NT_BLOCKS) do xl/xr transform; rest do degree hist ----
__global__ __launch_bounds__(256)
void k_pre(const float* __restrict__ x,
           const float* __restrict__ Wl, const float* __restrict__ bl,
           const float* __restrict__ Wr, const float* __restrict__ br,
           float* __restrict__ xl, float* __restrict__ xr,
           const int* __restrict__ ei, int* __restrict__ cnt_in,
           int* __restrict__ deg_out) {
    if ((int)blockIdx.x >= NT_BLOCKS) {      // histogram part (6250 blocks)
        int e = ((int)blockIdx.x - NT_BLOCKS) * 256 + threadIdx.x;
        int s = ei[e], d = ei[E + e];
        atomicAdd(&cnt_in[d], 1);
        if (s != d) atomicAdd(&deg_out[s], 1);
        return;
    }
    __shared__ float sWl[128 * 16];
    __shared__ float sWr[128 * 16];
    int t = threadIdx.x;
    for (int i = t; i < 2048; i += 256) { sWl[i] = Wl[i]; sWr[i] = Wr[i]; }
    __syncthreads();
    int f = t & 15, nl = t >> 4;
    int n = blockIdx.x * 16 + nl;
    const float4* xv = reinterpret_cast<const float4*>(x + (size_t)n * 128);
    float aL = bl[f], aR = br[f];
#pragma unroll 8
    for (int k4 = 0; k4 < 32; ++k4) {
        float4 v = xv[k4];
        int k = k4 * 4;
        aL += v.x * sWl[(k + 0) * 16 + f]; aR += v.x * sWr[(k + 0) * 16 + f];
        aL += v.y * sWl[(k + 1) * 16 + f]; aR += v.y * sWr[(k + 1) * 16 + f];
        aL += v.z * sWl[(k + 2) * 16 + f]; aR += v.z * sWr[(k + 2) * 16 + f];
        aL += v.w * sWl[(k + 3) * 16 + f]; aR += v.w * sWr[(k + 3) * 16 + f];
    }
    xl[n * 16 + f] = aL;
    xr[n * 16 + f] = aR;
}

// ---------------- exclusive scan of cnt_in -> rowptr (single block) ----------------
__global__ __launch_bounds__(1024)
void k_scan(const int* __restrict__ cnt, int* __restrict__ rowptr, int n) {
    __shared__ int ssum[1024];
    int t = threadIdx.x;
    const int chunk = 52;
    int lo = t * chunk;
    int hi = lo + chunk; if (hi > n) hi = n; if (lo > n) lo = n;
    int s = 0;
    for (int i = lo; i + 3 < hi; i += 4) {
        int4 v = *reinterpret_cast<const int4*>(cnt + i);
        s += v.x + v.y + v.z + v.w;
    }
    ssum[t] = s;
    __syncthreads();
    for (int off = 1; off < 1024; off <<= 1) {
        int v = (t >= off) ? ssum[t - off] : 0;
        __syncthreads();
        ssum[t] += v;
        __syncthreads();
    }
    int prefix = (t == 0) ? 0 : ssum[t - 1];
    for (int i = lo; i < hi; ++i) { rowptr[i] = prefix; prefix += cnt[i]; }
    if (t == 0) rowptr[n] = ssum[1023];
}

// ---------------- CSR placement ONLY: one packed 8B scatter per edge ----------
__global__ __launch_bounds__(256)
void k_edge_place(const int* __restrict__ ei, const int* __restrict__ rowptr,
                  int* __restrict__ ctr, int2* __restrict__ sedge) {
    int e = blockIdx.x * 256 + threadIdx.x;  // grid = E/256 exact
    int s = ei[e], d = ei[E + e];
    int p = rowptr[d] + atomicAdd(&ctr[d], 1);
    sedge[p] = make_int2(s, e);              // {src, eid}
}

// ---- fused per-node GAT, FEATURE-parallel lanes (lane f owns feature f),
//      serial over segment, online softmax with wave-uniform m/den and
//      SCALAR num/easum per lane. Per edge: sedge broadcast, ea/xl coalesced
//      64B rows; em via 16 shfl-broadcasts of a; alpha via 4-shfl reduce. ----
__global__ __launch_bounds__(256)
void k_gat(const int* __restrict__ rowptr, const int2* __restrict__ sedge,
           const float* __restrict__ ea, const float* __restrict__ xl,
           const float* __restrict__ xr, const int* __restrict__ deg_out,
           const float* __restrict__ We, const float* __restrict__ att,
           const float* __restrict__ gat_bias,
           const float* __restrict__ Wz0, const float* __restrict__ Wh0,
           float* __restrict__ h, float* __restrict__ hs,
           float* __restrict__ accz, float* __restrict__ acch,
           float* __restrict__ dinv) {
    __shared__ float sWe[256], sWz[256], sWh[256];
    __shared__ float satt[16];
    __shared__ float sxr[16][17];            // per-node xr row
    __shared__ float sbuf[16][17];
    int t = threadIdx.x;
    sWe[t] = We[t]; sWz[t] = Wz0[t]; sWh[t] = Wh0[t];
    if (t < 16) satt[t] = att[t];
    int f = t & 15, nl = t >> 4;
    int n = blockIdx.x * 16 + nl;            // grid = N/16 exact
    sxr[nl][f] = xr[n * 16 + f];
    __syncthreads();
    float xrf = sxr[nl][f];
    float attf = satt[f];
    int lo = rowptr[n], hi = rowptr[n + 1];
    float m = -3.0e38f, den = 0.f, num = 0.f, easum = 0.f;
    for (int i = lo; i < hi; ++i) {
        int2 se = sedge[i];                  // broadcast within group
        float a   = ea[(size_t)se.y * 16 + f];  // coalesced 64B row
        float xsf = xl[(size_t)se.x * 16 + f];  // coalesced 64B row
        easum += a;
        float em = 0.f;
#pragma unroll
        for (int j = 0; j < 16; ++j)
            em += __shfl(a, j, 16) * sWe[j * 16 + f];
        float mm = xsf + xrf + em;
        mm = mm > 0.f ? mm : 0.2f * mm;      // leaky_relu 0.2
        float part = mm * attf;
#pragma unroll
        for (int off = 1; off < 16; off <<= 1)
            part += __shfl_xor(part, off, 16);
        float alpha = part;                  // identical in all 16 lanes
        // branchless online-softmax (first edge: corr=exp(-inf)=0)
        float mnew = fmaxf(m, alpha);
        float corr = expf(m - mnew);
        float ex   = expf(alpha - mnew);
        den = den * corr + ex;
        num = num * corr + ex * xsf;
        m = mnew;
    }
    // self-loop alpha via linearity: ea_mean@We = (sum ea)@We / cnt
    sbuf[nl][f] = easum;
    __syncthreads();
    float cntf = (float)(hi - lo);
    float eml = 0.f;
#pragma unroll
    for (int j = 0; j < 16; ++j) eml += sbuf[nl][j] * sWe[j * 16 + f];
    eml /= fmaxf(cntf, 1.f);
    float xlf = xl[n * 16 + f];
    float m0 = xlf + xrf + eml;
    m0 = m0 > 0.f ? m0 : 0.2f * m0;
    float part2 = m0 * attf;
#pragma unroll
    for (int off = 1; off < 16; off <<= 1)
        part2 += __shfl_xor(part2, off, 16);
    float aloop = part2;
    float Mf = fmaxf(m, aloop);
    float sc2 = expf(m - Mf);                // no-edge node: exp(-inf)=0
    float exl = expf(aloop - Mf);
    num = num * sc2 + exl * xlf;
    float dent = den * sc2 + exl;
    float hv = num / (dent + 1e-16f) + gat_bias[f];
    float dg = (float)deg_out[n];
    float di = dg > 0.f ? rsqrtf(dg) : 0.f;
    h[n * 16 + f] = hv;
    hs[n * 16 + f] = di * hv;                // pre-scaled for cheb matvec
    if (f == 0) dinv[n] = di;
    // acc init = h @ W[.][0]
    __syncthreads();                          // reuse sbuf
    sbuf[nl][f] = hv;
    __syncthreads();
    float az = 0.f, ah = 0.f;
#pragma unroll
    for (int j = 0; j < 16; ++j) {
        float v = sbuf[nl][j];
        az += v * sWz[j * 16 + f];
        ah += v * sWh[j * 16 + f];
    }
    accz[n * 16 + f] = az;
    acch[n * 16 + f] = ah;
}

// ---- fused Cheb step: mv[n] = -dinv[n]*sum_{s!=n} Tins[s];
//      tv = mode ? 2*mv - Tprev : mv; optional stores; acc += tv@W[k] ----
__global__ __launch_bounds__(256)
void k_mvcomb(const int* __restrict__ rowptr, const int2* __restrict__ sedge,
              const float* __restrict__ dinv, const float* __restrict__ Tins,
              const float* __restrict__ Tprev, float* __restrict__ Tstore,
              float* __restrict__ Tscale_store,
              const float* __restrict__ Wzk, const float* __restrict__ Whk,
              float* __restrict__ accz, float* __restrict__ acch, int mode) {
    __shared__ float sWz[256], sWh[256];
    __shared__ float st[16][17];
    int t = threadIdx.x;
    sWz[t] = Wzk[t]; sWh[t] = Whk[t];
    int f = t & 15, nl = t >> 4;
    int n = blockIdx.x * 16 + nl;            // grid = N/16 exact
    int lo = rowptr[n], hi = rowptr[n + 1];
    float acc = 0.f;
    for (int i = lo; i < hi; ++i) {
        int s = sedge[i].x;                  // broadcast within group
        if (s != n) acc += Tins[s * 16 + f]; // Tins already dinv-scaled
    }
    float di = dinv[n];
    float tv = -di * acc;
    if (mode) tv = 2.f * tv - Tprev[n * 16 + f];
    if (Tstore)       Tstore[n * 16 + f] = tv;
    if (Tscale_store) Tscale_store[n * 16 + f] = di * tv;
    st[nl][f] = tv;
    __syncthreads();
    float az = accz[n * 16 + f], ah = acch[n * 16 + f];
#pragma unroll
    for (int j = 0; j < 16; ++j) {
        float v = st[nl][j];
        az += v * sWz[j * 16 + f];
        ah += v * sWh[j * 16 + f];
    }
    accz[n * 16 + f] = az;
    acch[n * 16 + f] = ah;
}

// ---- last Cheb step fused with GRU combine + per-node MLP + out row 0 ----
__global__ __launch_bounds__(256)
void k_mvfinal(const int* __restrict__ rowptr, const int2* __restrict__ sedge,
               const float* __restrict__ dinv, const float* __restrict__ Tins,
               const float* __restrict__ Tprev,
               const float* __restrict__ Wzk, const float* __restrict__ Whk,
               const float* __restrict__ accz, const float* __restrict__ acch,
               const float* __restrict__ cheb_b,
               const float* __restrict__ W1, const float* __restrict__ b1,
               const float* __restrict__ W2, const float* __restrict__ b2,
               float* __restrict__ out) {
    __shared__ float sWz[256], sWh[256];
    __shared__ float st[16][17];
    int t = threadIdx.x;
    sWz[t] = Wzk[t]; sWh[t] = Whk[t];
    int f = t & 15, nl = t >> 4;
    int n = blockIdx.x * 16 + nl;            // grid = N/16 exact
    int lo = rowptr[n], hi = rowptr[n + 1];
    float acc = 0.f;
    for (int i = lo; i < hi; ++i) {
        int s = sedge[i].x;
        if (s != n) acc += Tins[s * 16 + f];
    }
    float tv = -dinv[n] * acc;
    tv = 2.f * tv - Tprev[n * 16 + f];        // T3 = 2 L T2 - T1
    st[nl][f] = tv;
    __syncthreads();
    float az = accz[n * 16 + f], ah = acch[n * 16 + f];
#pragma unroll
    for (int j = 0; j < 16; ++j) {
        float v = st[nl][j];
        az += v * sWz[j * 16 + f];
        ah += v * sWh[j * 16 + f];
    }
    // GRU (H0=0): Z = sigmoid(az + b[0] + b[1]); Ht = tanh(ah + b[4] + b[5])
    float z  = 1.f / (1.f + expf(-(az + cheb_b[f] + cheb_b[16 + f])));
    float ht = tanhf(ah + cheb_b[64 + f] + cheb_b[80 + f]);
    float H = (1.f - z) * ht;
    __syncthreads();                          // reuse st
    st[nl][f] = H;
    __syncthreads();
    float hid[4];
#pragma unroll
    for (int cc = 0; cc < 4; ++cc) {
        float v = b1[cc];
#pragma unroll
        for (int j = 0; j < 16; ++j) v += st[nl][j] * W1[j * 4 + cc];
        hid[cc] = fmaxf(v, 0.f);
    }
    if (f < 8) {
        float v = b2[f];
#pragma unroll
        for (int cc = 0; cc < 4; ++cc) v += hid[cc] * W2[cc * 8 + f];
        out[(size_t)(n + 1) * 8 + f] = v;
    }
    if (blockIdx.x == 0 && t == 0) {          // segment 0 is empty -> H = 0
        float h0[4];
#pragma unroll
        for (int cc = 0; cc < 4; ++cc) h0[cc] = fmaxf(b1[cc], 0.f);
#pragma unroll
        for (int o = 0; o < 8; ++o) {
            float v = b2[o];
#pragma unroll
            for (int cc = 0; cc < 4; ++cc) v += h0[cc] * W2[cc * 8 + o];
            out[o] = v;
        }
    }
}

extern "C" void kernel_launch(void* const* d_in, const int* in_sizes, int n_in,
                              void* d_out, int out_size, void* d_ws, size_t ws_size,
                              hipStream_t stream) {
    const float* x    = (const float*)d_in[0];
    const int*   ei   = (const int*)d_in[1];
    const float* ea   = (const float*)d_in[2];
    const float* Wl   = (const float*)d_in[3];
    const float* bl   = (const float*)d_in[4];
    const float* Wr   = (const float*)d_in[5];
    const float* br   = (const float*)d_in[6];
    const float* We   = (const float*)d_in[7];
    const float* att  = (const float*)d_in[8];
    const float* gatb = (const float*)d_in[9];
    const float* chW  = (const float*)d_in[10];  // [6][4][16][16]
    const float* chb  = (const float*)d_in[11];  // [6][16]
    const float* W1   = (const float*)d_in[12];
    const float* b1   = (const float*)d_in[13];
    const float* W2   = (const float*)d_in[14];
    const float* b2   = (const float*)d_in[15];
    float* out = (float*)d_out;

    char* w = (char*)d_ws;
    size_t off = 0;
    auto alloc = [&](size_t elems) {
        off = (off + 15) & ~(size_t)15;       // keep float4/int2 alignment
        void* p = w + off;
        off += elems * 4;
        return p;
    };
    // zeroed region: cnt_in / deg_out / ctr contiguous (3N ints)
    int*   cnt_in  = (int*)alloc(N);
    int*   deg_out = (int*)alloc(N);
    int*   ctr     = (int*)alloc(N);
    int*   rowptr  = (int*)alloc(N + 2);
    float* xl      = (float*)alloc(16 * N);
    float* xr      = (float*)alloc(16 * N);
    int2*  sedge   = (int2*)alloc(2 * (size_t)E);  // {src, eid} packed
    float* dinv    = (float*)alloc(N);
    float* h       = (float*)alloc(16 * N);
    float* hs      = (float*)alloc(16 * N);   // dinv-scaled h
    float* accz    = (float*)alloc(16 * N);
    float* acch    = (float*)alloc(16 * N);
    float* T1      = (float*)alloc(16 * N);   // unscaled T1 (Tprev for step 3)
    float* Tsa     = (float*)alloc(16 * N);   // scaled current
    float* Tsb     = (float*)alloc(16 * N);
    (void)ws_size; (void)in_sizes; (void)n_in; (void)out_size;

    hipMemsetAsync(cnt_in, 0, (size_t)3 * N * sizeof(int), stream);

    k_pre<<<NT_BLOCKS + E / 256, 256, 0, stream>>>(x, Wl, bl, Wr, br, xl, xr,
                                                   ei, cnt_in, deg_out);
    k_scan<<<1, 1024, 0, stream>>>(cnt_in, rowptr, N);
    k_edge_place<<<E / 256, 256, 0, stream>>>(ei, rowptr, ctr, sedge);
    // cheb_W block k of cheb index i is at (i*4+k)*256 ; i=0 -> z path, i=4 -> h path
    k_gat<<<N / 16, 256, 0, stream>>>(rowptr, sedge, ea, xl, xr, deg_out, We, att,
                                      gatb, chW + 0 * 256, chW + 16 * 256,
                                      h, hs, accz, acch, dinv);
    // T1 = L h            ; acc += T1@W[1]   (store T1 unscaled + scaled)
    k_mvcomb<<<N / 16, 256, 0, stream>>>(rowptr, sedge, dinv, hs, (const float*)nullptr,
                                         T1, Tsa, chW + 1 * 256, chW + 17 * 256,
                                         accz, acch, 0);
    // T2 = 2 L T1 - h     ; acc += T2@W[2]   (store scaled only)
    k_mvcomb<<<N / 16, 256, 0, stream>>>(rowptr, sedge, dinv, Tsa, h,
                                         (float*)nullptr, Tsb, chW + 2 * 256, chW + 18 * 256,
                                         accz, acch, 1);
    // T3 = 2 L T2 - T1 fused with GRU + MLP + out
    k_mvfinal<<<N / 16, 256, 0, stream>>>(rowptr, sedge, dinv, Tsb, T1,
                                          chW + 3 * 256, chW + 19 * 256,
                                          accz, acch, chb, W1, b1, W2, b2, out);
}